// Round 9
// baseline (251.418 us; speedup 1.0000x reference)
//
#include <hip/hip_runtime.h>

#define HID 128
#define NRBF 20
#define KNN 16
#define NNODE 4096
#define NBATCH 8
#define CAP 112

typedef __attribute__((ext_vector_type(8))) short short8;
typedef __attribute__((ext_vector_type(4))) float f32x4;

// branchless RNE f32->bf16 (inputs finite here)
__device__ __forceinline__ short f2bf(float x) {
  unsigned u = __builtin_bit_cast(unsigned, x);
  u = u + 0x7FFFu + ((u >> 16) & 1u);
  return (short)(u >> 16);
}
__device__ __forceinline__ float silu_f(float x) {
  return x * __builtin_amdgcn_rcpf(1.0f + __expf(-x));  // ~1e-7 rel err << bf16 rounding
}
__device__ __forceinline__ short8 cv8(const float* p) {
  f32x4 a = *(const f32x4*)p;
  f32x4 b = *(const f32x4*)(p + 4);
  short8 r;
  r[0]=f2bf(a[0]); r[1]=f2bf(a[1]); r[2]=f2bf(a[2]); r[3]=f2bf(a[3]);
  r[4]=f2bf(b[0]); r[5]=f2bf(b[1]); r[6]=f2bf(b[2]); r[7]=f2bf(b[3]);
  return r;
}

// ---------------------------------------------------------------------------
// Kernel 0: h (f32) -> hb (bf16), once. BW-bound (~3-5 us).
// ---------------------------------------------------------------------------
__global__ __launch_bounds__(256)
void hcvt_kernel(const float* __restrict__ h, short* __restrict__ hb)
{
  size_t i = ((size_t)blockIdx.x * 256 + threadIdx.x) * 8;
  *(short8*)(hb + i) = cv8(h + i);
}

// ---------------------------------------------------------------------------
// Kernel 1: exact kNN (top-16, stable index tiebreak), f32. (unchanged R8)
// ---------------------------------------------------------------------------
__global__ __launch_bounds__(512)
void knn_kernel(const float* __restrict__ pos,
                int* __restrict__ eidx, float* __restrict__ edist)
{
  __shared__ float pX[NNODE], pY[NNODE], pZ[NNODE];   // 48 KB
  __shared__ float d2b[8][4][CAP];                    // 14 KB
  __shared__ int   jb[8][4][CAP];                     // 14 KB
  __shared__ int   cntL[8][4];

  const int tid  = threadIdx.x;
  const int wv   = tid >> 6;
  const int lane = tid & 63;
  const int b    = blockIdx.x >> 7;
  const int grp  = blockIdx.x & 127;

  const float* pb = pos + (size_t)b * NNODE * 3;
  for (int idx = tid; idx < NNODE; idx += 512) {
    pX[idx] = pb[idx*3]; pY[idx] = pb[idx*3+1]; pZ[idx] = pb[idx*3+2];
  }
  __syncthreads();

  const int i0 = grp * 32 + wv * 4;
  float pix[4], piy[4], piz[4];
  #pragma unroll
  for (int n = 0; n < 4; ++n) { pix[n]=pX[i0+n]; piy[n]=pY[i0+n]; piz[n]=pZ[i0+n]; }

  // pass 1: per-lane strip minima (self included, d2=0 exact)
  float vmin[4] = {3.0e38f, 3.0e38f, 3.0e38f, 3.0e38f};
  #pragma unroll 4
  for (int t = 0; t < 64; ++t) {
    const int j = t * 64 + lane;
    const float x = pX[j], y = pY[j], z = pZ[j];
    #pragma unroll
    for (int n = 0; n < 4; ++n) {
      float dx = __fsub_rn(pix[n], x);
      float dy = __fsub_rn(piy[n], y);
      float dz = __fsub_rn(piz[n], z);
      float d2 = __fadd_rn(__fadd_rn(__fmul_rn(dx,dx), __fmul_rn(dy,dy)), __fmul_rn(dz,dz));
      vmin[n] = fminf(vmin[n], d2);
    }
  }

  float Ts[4];
  #pragma unroll
  for (int n = 0; n < 4; ++n) {
    float v = vmin[n];
    #pragma unroll
    for (int k = 2; k <= 64; k <<= 1) {
      #pragma unroll
      for (int jj = k >> 1; jj > 0; jj >>= 1) {
        float o = __shfl_xor(v, jj);
        const bool up   = ((lane & k) == 0);
        const bool lowl = ((lane & jj) == 0);
        float mn = fminf(v, o), mx = fmaxf(v, o);
        v = (up == lowl) ? mn : mx;
      }
    }
    Ts[n] = __shfl(v, 16);   // element 16: >= true 16th non-self distance
  }

  if (lane < 4) cntL[wv][lane] = 0;
  #pragma unroll 2
  for (int t = 0; t < 64; ++t) {
    const int j = t * 64 + lane;
    const float x = pX[j], y = pY[j], z = pZ[j];
    #pragma unroll
    for (int n = 0; n < 4; ++n) {
      float dx = __fsub_rn(pix[n], x);
      float dy = __fsub_rn(piy[n], y);
      float dz = __fsub_rn(piz[n], z);
      float d2 = __fadd_rn(__fadd_rn(__fmul_rn(dx,dx), __fmul_rn(dy,dy)), __fmul_rn(dz,dz));
      if ((j != i0 + n) && (d2 <= Ts[n])) {
        int p = atomicAdd(&cntL[wv][n], 1);
        if (p < CAP) { d2b[wv][n][p] = d2; jb[wv][n][p] = j; }
      }
    }
  }

  #pragma unroll 1
  for (int n = 0; n < 4; ++n) {
    int cnt = cntL[wv][n];
    if (cnt > CAP) cnt = CAP;
    for (int s = lane; s < cnt; s += 64) {
      float dm = d2b[wv][n][s]; int jm = jb[wv][n][s];
      int rank = 0;
      for (int c = 0; c < cnt; ++c) {
        float dc = d2b[wv][n][c]; int jc = jb[wv][n][c];
        if (dc < dm || (dc == dm && jc < jm)) ++rank;
      }
      if (rank < KNN) {
        size_t base = ((size_t)b * NNODE + i0 + n) * KNN;
        eidx[base + rank]  = b * NNODE + jm;
        edist[base + rank] = sqrtf(__fadd_rn(dm, 1e-8f));
      }
    }
  }
}

// ---------------------------------------------------------------------------
// Kernel 2: edge MLP + mask + aggregate.
// 1024-thread/16-wave blocks -> 4 waves/SIMD (VGPR 116 <= 128 cap), ILP-2.
// Per-wave m1 buffer halved to [16][64] (2 KB), processed in two col-halves
// so total LDS stays 139 KB. Swizzle: 16B-slot ^= (row&7).
// ---------------------------------------------------------------------------
#define ENPW 8

template<bool HBF>
__global__ __launch_bounds__(1024)
void edge_kernel(const float* __restrict__ h, const short* __restrict__ hb,
                 const int* __restrict__ eidx, const float* __restrict__ edist,
                 const float* __restrict__ ew1, const float* __restrict__ eb1,
                 const float* __restrict__ ew2, const float* __restrict__ eb2,
                 float* __restrict__ agg)
{
  __shared__ __attribute__((aligned(16))) short8 F1[9*8*64];   // 73,728 B
  __shared__ __attribute__((aligned(16))) short8 F2[4*8*64];   // 32,768 B
  __shared__ __attribute__((aligned(16))) short m1s[16][1024]; // 32,768 B

  const int tid = threadIdx.x;
  for (int f = tid; f < 9*8*64; f += 1024) {
    int kc = f >> 9, rem = f & 511, nf = rem >> 6, ln = rem & 63;
    int kb = kc*32 + (ln >> 4)*8, col = nf*16 + (ln & 15);
    short8 v;
    #pragma unroll
    for (int e = 0; e < 8; ++e) {
      int k = kb + e;
      v[e] = (k < 276) ? f2bf(ew1[k*128 + col]) : (short)0;
    }
    F1[f] = v;
  }
  for (int f = tid; f < 4*8*64; f += 1024) {
    int kc = f >> 9, rem = f & 511, nf = rem >> 6, ln = rem & 63;
    int kb = kc*32 + (ln >> 4)*8, col = nf*16 + (ln & 15);
    short8 v;
    #pragma unroll
    for (int e = 0; e < 8; ++e) v[e] = f2bf(ew2[(kb + e)*128 + col]);
    F2[f] = v;
  }
  __syncthreads();

  const int wv = tid >> 6, lane = tid & 63;
  const int lo = lane & 15, hi = lane >> 4;
  short* m1w = &m1s[wv][0];

  float b1v[8], b2v[8];
  #pragma unroll
  for (int nf = 0; nf < 8; ++nf) {
    b1v[nf] = eb1[nf*16 + lo];
    b2v[nf] = eb2[nf*16 + lo];
  }
  // half-col m1 addressing: buffer [16 rows][64 cols] bf16, 16B slots 0..7/row
  // write: row=hi*4+q, col=nfl*16+lo -> slot=nfl*2+(lo>>3), ^=(row&7)
  // read : row=lo, slot=kcl*4+hi, ^=(lo&7)
  int wrow[4], wkey[4], rb[2];
  #pragma unroll
  for (int q = 0; q < 4; ++q) {
    int row = hi*4 + q;
    wrow[q] = row << 7;
    wkey[q] = row & 7;
  }
  const int inb = (lo & 7) << 1;
  const int slotb0 = (lo >> 3);      // + nfl*2
  #pragma unroll
  for (int kcl = 0; kcl < 2; ++kcl)
    rb[kcl] = (lo << 7) + (((kcl*4 + hi) ^ (lo & 7)) << 4);

  const f32x4 zero4 = {0.f, 0.f, 0.f, 0.f};
  const int nbase = (blockIdx.x * 16 + wv) * ENPW;

  #pragma unroll 1
  for (int it = 0; it < ENPW/2; ++it) {
    const int nA = nbase + it*2, nB = nA + 1;
    int jgA = eidx[(size_t)nA*KNN + lo] & (NBATCH*NNODE - 1);
    int jgB = eidx[(size_t)nB*KNN + lo] & (NBATCH*NNODE - 1);
    const float deA = edist[(size_t)nA*KNN + lo];
    const float deB = edist[(size_t)nB*KNN + lo];

    short8 aIA[4], aJA[4], aIB[4], aJB[4];
    #pragma unroll
    for (int kc = 0; kc < 4; ++kc) {
      if constexpr (HBF) {
        aIA[kc] = *(const short8*)(hb + (size_t)nA*HID  + kc*32 + hi*8);
        aJA[kc] = *(const short8*)(hb + (size_t)jgA*HID + kc*32 + hi*8);
        aIB[kc] = *(const short8*)(hb + (size_t)nB*HID  + kc*32 + hi*8);
        aJB[kc] = *(const short8*)(hb + (size_t)jgB*HID + kc*32 + hi*8);
      } else {
        aIA[kc] = cv8(h + (size_t)nA*HID  + kc*32 + hi*8);
        aJA[kc] = cv8(h + (size_t)jgA*HID + kc*32 + hi*8);
        aIB[kc] = cv8(h + (size_t)nB*HID  + kc*32 + hi*8);
        aJB[kc] = cv8(h + (size_t)jgB*HID + kc*32 + hi*8);
      }
    }
    short8 aRA, aRB;
    #pragma unroll
    for (int e = 0; e < 8; ++e) {
      const int r = hi*8 + e;
      float vA = 0.f, vB = 0.f;
      if (r < NRBF) {
        const float cr = (float)(r * (5.0/19.0));
        float tA = __fsub_rn(deA, cr), tB = __fsub_rn(deB, cr);
        vA = __expf(-16.0f * __fmul_rn(tA, tA));
        vB = __expf(-16.0f * __fmul_rn(tB, tB));
      }
      aRA[e] = f2bf(vA); aRB[e] = f2bf(vB);
    }

    f32x4 acc1A[8], acc1B[8];
    #pragma unroll
    for (int nf = 0; nf < 8; ++nf) { acc1A[nf] = zero4; acc1B[nf] = zero4; }
    __builtin_amdgcn_s_setprio(1);
    #pragma unroll
    for (int kc = 0; kc < 9; ++kc) {
      short8 aA = (kc < 4) ? aIA[kc] : ((kc < 8) ? aJA[kc-4] : aRA);
      short8 aB = (kc < 4) ? aIB[kc] : ((kc < 8) ? aJB[kc-4] : aRB);
      #pragma unroll
      for (int nf = 0; nf < 8; ++nf) {
        short8 bf = F1[(kc*8 + nf)*64 + lane];     // one read feeds 2 MFMAs
        acc1A[nf] = __builtin_amdgcn_mfma_f32_16x16x32_bf16(aA, bf, acc1A[nf], 0,0,0);
        acc1B[nf] = __builtin_amdgcn_mfma_f32_16x16x32_bf16(aB, bf, acc1B[nf], 0,0,0);
      }
    }
    __builtin_amdgcn_s_setprio(0);

    // m1 transpose through per-wave [16][64] buffer, two col-halves per node.
    short8 a2A[4], a2B[4];
    #pragma unroll
    for (int hh = 0; hh < 2; ++hh) {
      #pragma unroll
      for (int nfl = 0; nfl < 4; ++nfl) {
        int nf = hh*4 + nfl;
        int slot = nfl*2 + slotb0;
        #pragma unroll
        for (int q = 0; q < 4; ++q) {
          float s = silu_f(acc1A[nf][q] + b1v[nf]);
          int off = wrow[q] + ((slot ^ wkey[q]) << 4) + inb;
          *(short*)((char*)m1w + off) = f2bf(s);
        }
      }
      #pragma unroll
      for (int kcl = 0; kcl < 2; ++kcl)
        a2A[hh*2 + kcl] = *(const short8*)((char*)m1w + rb[kcl]);
    }
    #pragma unroll
    for (int hh = 0; hh < 2; ++hh) {
      #pragma unroll
      for (int nfl = 0; nfl < 4; ++nfl) {
        int nf = hh*4 + nfl;
        int slot = nfl*2 + slotb0;
        #pragma unroll
        for (int q = 0; q < 4; ++q) {
          float s = silu_f(acc1B[nf][q] + b1v[nf]);
          int off = wrow[q] + ((slot ^ wkey[q]) << 4) + inb;
          *(short*)((char*)m1w + off) = f2bf(s);
        }
      }
      #pragma unroll
      for (int kcl = 0; kcl < 2; ++kcl)
        a2B[hh*2 + kcl] = *(const short8*)((char*)m1w + rb[kcl]);
    }

    f32x4 acc2A[8], acc2B[8];
    #pragma unroll
    for (int nf = 0; nf < 8; ++nf) { acc2A[nf] = zero4; acc2B[nf] = zero4; }
    __builtin_amdgcn_s_setprio(1);
    #pragma unroll
    for (int kc = 0; kc < 4; ++kc) {
      #pragma unroll
      for (int nf = 0; nf < 8; ++nf) {
        short8 bf = F2[(kc*8 + nf)*64 + lane];
        acc2A[nf] = __builtin_amdgcn_mfma_f32_16x16x32_bf16(a2A[kc], bf, acc2A[nf], 0,0,0);
        acc2B[nf] = __builtin_amdgcn_mfma_f32_16x16x32_bf16(a2B[kc], bf, acc2B[nf], 0,0,0);
      }
    }
    __builtin_amdgcn_s_setprio(0);

    float dqA[4], dqB[4];
    #pragma unroll
    for (int q = 0; q < 4; ++q) {
      dqA[q] = __shfl(deA, hi*4 + q);   // lane s<16 holds edist[node*16+s]
      dqB[q] = __shfl(deB, hi*4 + q);
    }
    #pragma unroll
    for (int nf = 0; nf < 8; ++nf) {
      float sA = 0.f, sB = 0.f;
      #pragma unroll
      for (int q = 0; q < 4; ++q) {
        float mA = silu_f(acc2A[nf][q] + b2v[nf]);
        float mB = silu_f(acc2B[nf][q] + b2v[nf]);
        sA += (dqA[q] < 5.0f) ? mA : 0.f;
        sB += (dqB[q] < 5.0f) ? mB : 0.f;
      }
      sA += __shfl_xor(sA, 16); sA += __shfl_xor(sA, 32);
      sB += __shfl_xor(sB, 16); sB += __shfl_xor(sB, 32);
      if (hi == 0) {
        agg[(size_t)nA*HID + nf*16 + lo] = sA;
        agg[(size_t)nB*HID + nf*16 + lo] = sB;
      }
    }
  }
}

// ---------------------------------------------------------------------------
// Kernel 3: node MLP + residual + LayerNorm, agg==out in-place. (unchanged R8)
// ---------------------------------------------------------------------------
template<bool HBF>
__global__ __launch_bounds__(512)
void node_kernel(const float* __restrict__ h, const short* __restrict__ hb,
                 const float* agg,
                 const float* __restrict__ nw1, const float* __restrict__ nb1,
                 const float* __restrict__ nw2, const float* __restrict__ nb2,
                 const float* __restrict__ gam, const float* __restrict__ bet,
                 float* out)
{
  __shared__ __attribute__((aligned(16))) short8 G1[8*8*64];   // 65,536 B
  __shared__ __attribute__((aligned(16))) short8 G2[4*8*64];   // 32,768 B
  __shared__ __attribute__((aligned(16))) short m1s[8][2048];  // 32,768 B

  const int tid = threadIdx.x;
  for (int f = tid; f < 8*8*64; f += 512) {
    int kc = f >> 9, rem = f & 511, nf = rem >> 6, ln = rem & 63;
    int kb = kc*32 + (ln >> 4)*8, col = nf*16 + (ln & 15);
    short8 v;
    #pragma unroll
    for (int e = 0; e < 8; ++e) v[e] = f2bf(nw1[(kb + e)*128 + col]);
    G1[f] = v;
  }
  for (int f = tid; f < 4*8*64; f += 512) {
    int kc = f >> 9, rem = f & 511, nf = rem >> 6, ln = rem & 63;
    int kb = kc*32 + (ln >> 4)*8, col = nf*16 + (ln & 15);
    short8 v;
    #pragma unroll
    for (int e = 0; e < 8; ++e) v[e] = f2bf(nw2[(kb + e)*128 + col]);
    G2[f] = v;
  }
  __syncthreads();

  const int wv = tid >> 6, lane = tid & 63;
  const int lo = lane & 15, hi = lane >> 4;
  short* m1w = &m1s[wv][0];

  float b1v[8], b2v[8], gv[8], bv[8];
  #pragma unroll
  for (int nf = 0; nf < 8; ++nf) {
    b1v[nf] = nb1[nf*16 + lo];
    b2v[nf] = nb2[nf*16 + lo];
    gv[nf]  = gam[nf*16 + lo];
    bv[nf]  = bet[nf*16 + lo];
  }
  const f32x4 zero4 = {0.f, 0.f, 0.f, 0.f};

  const int row0 = (blockIdx.x * 8 + wv) * 16;

  const float* hrow = h   + (size_t)(row0 + lo) * HID;
  const float* arow = agg + (size_t)(row0 + lo) * HID;
  const short* hbrow = hb + (size_t)(row0 + lo) * HID;

  f32x4 acc1[8];
  #pragma unroll
  for (int nf = 0; nf < 8; ++nf) acc1[nf] = zero4;
  #pragma unroll
  for (int kc = 0; kc < 8; ++kc) {
    short8 a;
    if (kc < 4) {
      if constexpr (HBF) a = *(const short8*)(hbrow + kc*32 + hi*8);
      else               a = cv8(hrow + kc*32 + hi*8);
    } else {
      a = cv8(arow + (kc - 4)*32 + hi*8);
    }
    #pragma unroll
    for (int nf = 0; nf < 8; ++nf) {
      short8 bf = G1[(kc*8 + nf)*64 + lane];
      acc1[nf] = __builtin_amdgcn_mfma_f32_16x16x32_bf16(a, bf, acc1[nf], 0,0,0);
    }
  }

  #pragma unroll
  for (int nf = 0; nf < 8; ++nf) {
    #pragma unroll
    for (int q = 0; q < 4; ++q) {
      float s = silu_f(acc1[nf][q] + b1v[nf]);
      int row = hi*4 + q, col = nf*16 + lo;
      int byteoff = ((row << 8) + (col << 1)) ^ ((row & 7) << 4);
      *(short*)((char*)m1w + byteoff) = f2bf(s);
    }
  }

  f32x4 acc2[8];
  #pragma unroll
  for (int nf = 0; nf < 8; ++nf) acc2[nf] = zero4;
  #pragma unroll
  for (int kc = 0; kc < 4; ++kc) {
    int byteA = ((lo << 8) + ((kc*32 + hi*8) << 1)) ^ ((lo & 7) << 4);
    short8 a = *(const short8*)((char*)m1w + byteA);
    #pragma unroll
    for (int nf = 0; nf < 8; ++nf) {
      short8 bf = G2[(kc*8 + nf)*64 + lane];
      acc2[nf] = __builtin_amdgcn_mfma_f32_16x16x32_bf16(a, bf, acc2[nf], 0,0,0);
    }
  }

  float xv[4][8];
  #pragma unroll
  for (int nf = 0; nf < 8; ++nf) {
    #pragma unroll
    for (int q = 0; q < 4; ++q) {
      xv[q][nf] = acc2[nf][q] + b2v[nf]
                + h[(size_t)(row0 + hi*4 + q) * HID + nf*16 + lo];
    }
  }

  #pragma unroll
  for (int q = 0; q < 4; ++q) {
    float s = 0.0f;
    #pragma unroll
    for (int nf = 0; nf < 8; ++nf) s += xv[q][nf];
    s += __shfl_xor(s, 1); s += __shfl_xor(s, 2);
    s += __shfl_xor(s, 4); s += __shfl_xor(s, 8);
    float mu = s * 0.0078125f;
    float t = 0.0f;
    #pragma unroll
    for (int nf = 0; nf < 8; ++nf) { float d = xv[q][nf] - mu; t += d * d; }
    t += __shfl_xor(t, 1); t += __shfl_xor(t, 2);
    t += __shfl_xor(t, 4); t += __shfl_xor(t, 8);
    float inv = 1.0f / sqrtf(t * 0.0078125f + 1e-5f);
    #pragma unroll
    for (int nf = 0; nf < 8; ++nf) {
      float y = (xv[q][nf] - mu) * inv * gv[nf] + bv[nf];
      out[(size_t)(row0 + hi*4 + q) * HID + nf*16 + lo] = y;
    }
  }
}

// ---------------------------------------------------------------------------
extern "C" void kernel_launch(void* const* d_in, const int* in_sizes, int n_in,
                              void* d_out, int out_size, void* d_ws, size_t ws_size,
                              hipStream_t stream) {
  (void)in_sizes; (void)n_in; (void)out_size;
  const float* h   = (const float*)d_in[0];
  const float* pos = (const float*)d_in[1];
  const float* ew1 = (const float*)d_in[2];
  const float* eb1 = (const float*)d_in[3];
  const float* ew2 = (const float*)d_in[4];
  const float* eb2 = (const float*)d_in[5];
  const float* nw1 = (const float*)d_in[6];
  const float* nb1 = (const float*)d_in[7];
  const float* nw2 = (const float*)d_in[8];
  const float* nb2 = (const float*)d_in[9];
  const float* gam = (const float*)d_in[10];
  const float* bet = (const float*)d_in[11];

  // ws: eidx 2MB | edist 2MB | hb(bf16 h) 8.4MB (optional). agg lives in d_out.
  const size_t base_need = (size_t)NBATCH * NNODE * KNN * 8;                 // 4 MB
  const size_t hbf_need  = base_need + (size_t)NBATCH * NNODE * HID * 2;     // +8.4 MB
  if (ws_size < base_need) return;
  const bool use_hbf = (ws_size >= hbf_need);

  char* wsp = (char*)d_ws;
  int*   eidx  = (int*)wsp;
  float* edist = (float*)(wsp + (size_t)NBATCH * NNODE * KNN * 4);
  short* hb    = (short*)(wsp + base_need);
  float* agg   = (float*)d_out;

  if (use_hbf) {
    hcvt_kernel<<<dim3(2048), dim3(256), 0, stream>>>(h, hb);
  }
  knn_kernel<<<dim3(1024), dim3(512), 0, stream>>>(pos, eidx, edist);
  if (use_hbf) {
    edge_kernel<true ><<<dim3(256), dim3(1024), 0, stream>>>(h, hb, eidx, edist,
                                                             ew1, eb1, ew2, eb2, agg);
    node_kernel<true ><<<dim3(256), dim3(512), 0, stream>>>(h, hb, agg, nw1, nb1,
                                                            nw2, nb2, gam, bet, (float*)d_out);
  } else {
    edge_kernel<false><<<dim3(256), dim3(1024), 0, stream>>>(h, hb, eidx, edist,
                                                             ew1, eb1, ew2, eb2, agg);
    node_kernel<false><<<dim3(256), dim3(512), 0, stream>>>(h, hb, agg, nw1, nb1,
                                                            nw2, nb2, gam, bet, (float*)d_out);
  }
}

// Round 10
// 242.744 us; speedup vs baseline: 1.0357x; 1.0357x over previous
//
#include <hip/hip_runtime.h>

#define HID 128
#define NRBF 20
#define KNN 16
#define NNODE 4096
#define NBATCH 8
#define CAP 112

typedef __attribute__((ext_vector_type(8))) short short8;
typedef __attribute__((ext_vector_type(4))) float f32x4;

// branchless RNE f32->bf16 (inputs finite here)
__device__ __forceinline__ short f2bf(float x) {
  unsigned u = __builtin_bit_cast(unsigned, x);
  u = u + 0x7FFFu + ((u >> 16) & 1u);
  return (short)(u >> 16);
}
__device__ __forceinline__ float silu_f(float x) {
  return x * __builtin_amdgcn_rcpf(1.0f + __expf(-x));  // ~1e-7 rel err << bf16 rounding
}
__device__ __forceinline__ short8 cv8(const float* p) {
  f32x4 a = *(const f32x4*)p;
  f32x4 b = *(const f32x4*)(p + 4);
  short8 r;
  r[0]=f2bf(a[0]); r[1]=f2bf(a[1]); r[2]=f2bf(a[2]); r[3]=f2bf(a[3]);
  r[4]=f2bf(b[0]); r[5]=f2bf(b[1]); r[6]=f2bf(b[2]); r[7]=f2bf(b[3]);
  return r;
}

// ---------------------------------------------------------------------------
// Kernel 0: h (f32) -> hb (bf16), once. BW-bound (~3-5 us).
// ---------------------------------------------------------------------------
__global__ __launch_bounds__(256)
void hcvt_kernel(const float* __restrict__ h, short* __restrict__ hb)
{
  size_t i = ((size_t)blockIdx.x * 256 + threadIdx.x) * 8;
  *(short8*)(hb + i) = cv8(h + i);
}

// ---------------------------------------------------------------------------
// Kernel 1: exact kNN (top-16, stable index tiebreak).
// Scans use FMA (fast d2); threshold inflated by (1+2e-6) so every true
// top-16 candidate under EXACT arithmetic provably passes the filter.
// Exact __f*_rn d2 recomputed for the <=CAP compacted candidates, then
// exact stable rank selection -> selected set identical to numpy.
// ---------------------------------------------------------------------------
__global__ __launch_bounds__(512)
void knn_kernel(const float* __restrict__ pos,
                int* __restrict__ eidx, float* __restrict__ edist)
{
  __shared__ float pX[NNODE], pY[NNODE], pZ[NNODE];   // 48 KB
  __shared__ float d2b[8][4][CAP];                    // 14 KB
  __shared__ int   jb[8][4][CAP];                     // 14 KB
  __shared__ int   cntL[8][4];

  const int tid  = threadIdx.x;
  const int wv   = tid >> 6;
  const int lane = tid & 63;
  const int b    = blockIdx.x >> 7;
  const int grp  = blockIdx.x & 127;

  const float* pb = pos + (size_t)b * NNODE * 3;
  for (int idx = tid; idx < NNODE; idx += 512) {
    pX[idx] = pb[idx*3]; pY[idx] = pb[idx*3+1]; pZ[idx] = pb[idx*3+2];
  }
  __syncthreads();

  const int i0 = grp * 32 + wv * 4;
  float pix[4], piy[4], piz[4];
  #pragma unroll
  for (int n = 0; n < 4; ++n) { pix[n]=pX[i0+n]; piy[n]=pY[i0+n]; piz[n]=pZ[i0+n]; }

  // pass 1: per-lane strip minima of FAST d2 (self included, =0 exactly)
  float vmin[4] = {3.0e38f, 3.0e38f, 3.0e38f, 3.0e38f};
  #pragma unroll 4
  for (int t = 0; t < 64; ++t) {
    const int j = t * 64 + lane;
    const float x = pX[j], y = pY[j], z = pZ[j];
    #pragma unroll
    for (int n = 0; n < 4; ++n) {
      float dx = pix[n] - x, dy = piy[n] - y, dz = piz[n] - z;
      float d2 = fmaf(dz, dz, fmaf(dy, dy, dx * dx));
      vmin[n] = fminf(vmin[n], d2);
    }
  }

  float Tp[4];
  #pragma unroll
  for (int n = 0; n < 4; ++n) {
    float v = vmin[n];
    #pragma unroll
    for (int k = 2; k <= 64; k <<= 1) {
      #pragma unroll
      for (int jj = k >> 1; jj > 0; jj >>= 1) {
        float o = __shfl_xor(v, jj);
        const bool up   = ((lane & k) == 0);
        const bool lowl = ((lane & jj) == 0);
        float mn = fminf(v, o), mx = fmaxf(v, o);
        v = (up == lowl) ? mn : mx;
      }
    }
    float Tf = __shfl(v, 16);          // elem 16: >= 16th non-self FAST dist
    Tp[n] = Tf * (1.0f + 2.0e-6f) + 1.0e-35f;  // covers fast<->exact skew
  }

  if (lane < 4) cntL[wv][lane] = 0;
  // pass 2: ONE batched FAST scan, compact indices only
  #pragma unroll 2
  for (int t = 0; t < 64; ++t) {
    const int j = t * 64 + lane;
    const float x = pX[j], y = pY[j], z = pZ[j];
    #pragma unroll
    for (int n = 0; n < 4; ++n) {
      float dx = pix[n] - x, dy = piy[n] - y, dz = piz[n] - z;
      float d2 = fmaf(dz, dz, fmaf(dy, dy, dx * dx));
      if ((j != i0 + n) && (d2 <= Tp[n])) {
        int p = atomicAdd(&cntL[wv][n], 1);
        if (p < CAP) jb[wv][n][p] = j;
      }
    }
  }

  // recompute EXACT d2 for compacted candidates, then exact stable selection
  #pragma unroll 1
  for (int n = 0; n < 4; ++n) {
    int cnt = cntL[wv][n];
    if (cnt > CAP) cnt = CAP;
    const int i = i0 + n;
    for (int s = lane; s < cnt; s += 64) {
      int j = jb[wv][n][s];
      float dx = __fsub_rn(pix[n], pX[j]);
      float dy = __fsub_rn(piy[n], pY[j]);
      float dz = __fsub_rn(piz[n], pZ[j]);
      d2b[wv][n][s] = __fadd_rn(__fadd_rn(__fmul_rn(dx,dx), __fmul_rn(dy,dy)),
                                __fmul_rn(dz,dz));
    }
    (void)i;
    for (int s = lane; s < cnt; s += 64) {
      float dm = d2b[wv][n][s]; int jm = jb[wv][n][s];
      int rank = 0;
      for (int c = 0; c < cnt; ++c) {
        float dc = d2b[wv][n][c]; int jc = jb[wv][n][c];
        if (dc < dm || (dc == dm && jc < jm)) ++rank;
      }
      if (rank < KNN) {
        size_t base = ((size_t)b * NNODE + i0 + n) * KNN;
        eidx[base + rank]  = b * NNODE + jm;
        edist[base + rank] = sqrtf(__fadd_rn(dm, 1e-8f));
      }
    }
  }
}

// ---------------------------------------------------------------------------
// Kernel 2: edge MLP + mask + aggregate.
// 1024-thread/16-wave blocks; __launch_bounds__(1024, 1) pins the register
// budget at 1 block/CU = 16 waves = 4 waves/SIMD -> 128 VGPRs >= the ~116
// this body needs (R9's missing 2nd arg let the heuristic target 64 -> spills).
// ---------------------------------------------------------------------------
#define ENPW 8

template<bool HBF>
__global__ __launch_bounds__(1024, 1)
void edge_kernel(const float* __restrict__ h, const short* __restrict__ hb,
                 const int* __restrict__ eidx, const float* __restrict__ edist,
                 const float* __restrict__ ew1, const float* __restrict__ eb1,
                 const float* __restrict__ ew2, const float* __restrict__ eb2,
                 float* __restrict__ agg)
{
  __shared__ __attribute__((aligned(16))) short8 F1[9*8*64];   // 73,728 B
  __shared__ __attribute__((aligned(16))) short8 F2[4*8*64];   // 32,768 B
  __shared__ __attribute__((aligned(16))) short m1s[16][1024]; // 32,768 B

  const int tid = threadIdx.x;
  for (int f = tid; f < 9*8*64; f += 1024) {
    int kc = f >> 9, rem = f & 511, nf = rem >> 6, ln = rem & 63;
    int kb = kc*32 + (ln >> 4)*8, col = nf*16 + (ln & 15);
    short8 v;
    #pragma unroll
    for (int e = 0; e < 8; ++e) {
      int k = kb + e;
      v[e] = (k < 276) ? f2bf(ew1[k*128 + col]) : (short)0;
    }
    F1[f] = v;
  }
  for (int f = tid; f < 4*8*64; f += 1024) {
    int kc = f >> 9, rem = f & 511, nf = rem >> 6, ln = rem & 63;
    int kb = kc*32 + (ln >> 4)*8, col = nf*16 + (ln & 15);
    short8 v;
    #pragma unroll
    for (int e = 0; e < 8; ++e) v[e] = f2bf(ew2[(kb + e)*128 + col]);
    F2[f] = v;
  }
  __syncthreads();

  const int wv = tid >> 6, lane = tid & 63;
  const int lo = lane & 15, hi = lane >> 4;
  short* m1w = &m1s[wv][0];

  float b1v[8], b2v[8];
  #pragma unroll
  for (int nf = 0; nf < 8; ++nf) {
    b1v[nf] = eb1[nf*16 + lo];
    b2v[nf] = eb2[nf*16 + lo];
  }
  // half-col m1 addressing: [16 rows][64 cols] bf16, 16B slots 0..7/row
  int wrow[4], wkey[4], rb[2];
  #pragma unroll
  for (int q = 0; q < 4; ++q) {
    int row = hi*4 + q;
    wrow[q] = row << 7;
    wkey[q] = row & 7;
  }
  const int inb = (lo & 7) << 1;
  const int slotb0 = (lo >> 3);      // + nfl*2
  #pragma unroll
  for (int kcl = 0; kcl < 2; ++kcl)
    rb[kcl] = (lo << 7) + (((kcl*4 + hi) ^ (lo & 7)) << 4);

  const f32x4 zero4 = {0.f, 0.f, 0.f, 0.f};
  const int nbase = (blockIdx.x * 16 + wv) * ENPW;

  #pragma unroll 1
  for (int it = 0; it < ENPW/2; ++it) {
    const int nA = nbase + it*2, nB = nA + 1;
    int jgA = eidx[(size_t)nA*KNN + lo] & (NBATCH*NNODE - 1);
    int jgB = eidx[(size_t)nB*KNN + lo] & (NBATCH*NNODE - 1);
    const float deA = edist[(size_t)nA*KNN + lo];
    const float deB = edist[(size_t)nB*KNN + lo];

    short8 aIA[4], aJA[4], aIB[4], aJB[4];
    #pragma unroll
    for (int kc = 0; kc < 4; ++kc) {
      if constexpr (HBF) {
        aIA[kc] = *(const short8*)(hb + (size_t)nA*HID  + kc*32 + hi*8);
        aJA[kc] = *(const short8*)(hb + (size_t)jgA*HID + kc*32 + hi*8);
        aIB[kc] = *(const short8*)(hb + (size_t)nB*HID  + kc*32 + hi*8);
        aJB[kc] = *(const short8*)(hb + (size_t)jgB*HID + kc*32 + hi*8);
      } else {
        aIA[kc] = cv8(h + (size_t)nA*HID  + kc*32 + hi*8);
        aJA[kc] = cv8(h + (size_t)jgA*HID + kc*32 + hi*8);
        aIB[kc] = cv8(h + (size_t)nB*HID  + kc*32 + hi*8);
        aJB[kc] = cv8(h + (size_t)jgB*HID + kc*32 + hi*8);
      }
    }
    short8 aRA, aRB;
    #pragma unroll
    for (int e = 0; e < 8; ++e) {
      const int r = hi*8 + e;
      float vA = 0.f, vB = 0.f;
      if (r < NRBF) {
        const float cr = (float)(r * (5.0/19.0));
        float tA = __fsub_rn(deA, cr), tB = __fsub_rn(deB, cr);
        vA = __expf(-16.0f * __fmul_rn(tA, tA));
        vB = __expf(-16.0f * __fmul_rn(tB, tB));
      }
      aRA[e] = f2bf(vA); aRB[e] = f2bf(vB);
    }

    f32x4 acc1A[8], acc1B[8];
    #pragma unroll
    for (int nf = 0; nf < 8; ++nf) { acc1A[nf] = zero4; acc1B[nf] = zero4; }
    __builtin_amdgcn_s_setprio(1);
    #pragma unroll
    for (int kc = 0; kc < 9; ++kc) {
      short8 aA = (kc < 4) ? aIA[kc] : ((kc < 8) ? aJA[kc-4] : aRA);
      short8 aB = (kc < 4) ? aIB[kc] : ((kc < 8) ? aJB[kc-4] : aRB);
      #pragma unroll
      for (int nf = 0; nf < 8; ++nf) {
        short8 bf = F1[(kc*8 + nf)*64 + lane];     // one read feeds 2 MFMAs
        acc1A[nf] = __builtin_amdgcn_mfma_f32_16x16x32_bf16(aA, bf, acc1A[nf], 0,0,0);
        acc1B[nf] = __builtin_amdgcn_mfma_f32_16x16x32_bf16(aB, bf, acc1B[nf], 0,0,0);
      }
    }
    __builtin_amdgcn_s_setprio(0);

    // m1 transpose through per-wave [16][64] buffer, two col-halves per node.
    short8 a2A[4], a2B[4];
    #pragma unroll
    for (int hh = 0; hh < 2; ++hh) {
      #pragma unroll
      for (int nfl = 0; nfl < 4; ++nfl) {
        int nf = hh*4 + nfl;
        int slot = nfl*2 + slotb0;
        #pragma unroll
        for (int q = 0; q < 4; ++q) {
          float s = silu_f(acc1A[nf][q] + b1v[nf]);
          int off = wrow[q] + ((slot ^ wkey[q]) << 4) + inb;
          *(short*)((char*)m1w + off) = f2bf(s);
        }
      }
      #pragma unroll
      for (int kcl = 0; kcl < 2; ++kcl)
        a2A[hh*2 + kcl] = *(const short8*)((char*)m1w + rb[kcl]);
    }
    #pragma unroll
    for (int hh = 0; hh < 2; ++hh) {
      #pragma unroll
      for (int nfl = 0; nfl < 4; ++nfl) {
        int nf = hh*4 + nfl;
        int slot = nfl*2 + slotb0;
        #pragma unroll
        for (int q = 0; q < 4; ++q) {
          float s = silu_f(acc1B[nf][q] + b1v[nf]);
          int off = wrow[q] + ((slot ^ wkey[q]) << 4) + inb;
          *(short*)((char*)m1w + off) = f2bf(s);
        }
      }
      #pragma unroll
      for (int kcl = 0; kcl < 2; ++kcl)
        a2B[hh*2 + kcl] = *(const short8*)((char*)m1w + rb[kcl]);
    }

    f32x4 acc2A[8], acc2B[8];
    #pragma unroll
    for (int nf = 0; nf < 8; ++nf) { acc2A[nf] = zero4; acc2B[nf] = zero4; }
    __builtin_amdgcn_s_setprio(1);
    #pragma unroll
    for (int kc = 0; kc < 4; ++kc) {
      #pragma unroll
      for (int nf = 0; nf < 8; ++nf) {
        short8 bf = F2[(kc*8 + nf)*64 + lane];
        acc2A[nf] = __builtin_amdgcn_mfma_f32_16x16x32_bf16(a2A[kc], bf, acc2A[nf], 0,0,0);
        acc2B[nf] = __builtin_amdgcn_mfma_f32_16x16x32_bf16(a2B[kc], bf, acc2B[nf], 0,0,0);
      }
    }
    __builtin_amdgcn_s_setprio(0);

    float dqA[4], dqB[4];
    #pragma unroll
    for (int q = 0; q < 4; ++q) {
      dqA[q] = __shfl(deA, hi*4 + q);   // lane s<16 holds edist[node*16+s]
      dqB[q] = __shfl(deB, hi*4 + q);
    }
    #pragma unroll
    for (int nf = 0; nf < 8; ++nf) {
      float sA = 0.f, sB = 0.f;
      #pragma unroll
      for (int q = 0; q < 4; ++q) {
        float mA = silu_f(acc2A[nf][q] + b2v[nf]);
        float mB = silu_f(acc2B[nf][q] + b2v[nf]);
        sA += (dqA[q] < 5.0f) ? mA : 0.f;
        sB += (dqB[q] < 5.0f) ? mB : 0.f;
      }
      sA += __shfl_xor(sA, 16); sA += __shfl_xor(sA, 32);
      sB += __shfl_xor(sB, 16); sB += __shfl_xor(sB, 32);
      if (hi == 0) {
        agg[(size_t)nA*HID + nf*16 + lo] = sA;
        agg[(size_t)nB*HID + nf*16 + lo] = sB;
      }
    }
  }
}

// ---------------------------------------------------------------------------
// Kernel 3: node MLP + residual + LayerNorm, agg==out in-place. (unchanged)
// ---------------------------------------------------------------------------
template<bool HBF>
__global__ __launch_bounds__(512)
void node_kernel(const float* __restrict__ h, const short* __restrict__ hb,
                 const float* agg,
                 const float* __restrict__ nw1, const float* __restrict__ nb1,
                 const float* __restrict__ nw2, const float* __restrict__ nb2,
                 const float* __restrict__ gam, const float* __restrict__ bet,
                 float* out)
{
  __shared__ __attribute__((aligned(16))) short8 G1[8*8*64];   // 65,536 B
  __shared__ __attribute__((aligned(16))) short8 G2[4*8*64];   // 32,768 B
  __shared__ __attribute__((aligned(16))) short m1s[8][2048];  // 32,768 B

  const int tid = threadIdx.x;
  for (int f = tid; f < 8*8*64; f += 512) {
    int kc = f >> 9, rem = f & 511, nf = rem >> 6, ln = rem & 63;
    int kb = kc*32 + (ln >> 4)*8, col = nf*16 + (ln & 15);
    short8 v;
    #pragma unroll
    for (int e = 0; e < 8; ++e) v[e] = f2bf(nw1[(kb + e)*128 + col]);
    G1[f] = v;
  }
  for (int f = tid; f < 4*8*64; f += 512) {
    int kc = f >> 9, rem = f & 511, nf = rem >> 6, ln = rem & 63;
    int kb = kc*32 + (ln >> 4)*8, col = nf*16 + (ln & 15);
    short8 v;
    #pragma unroll
    for (int e = 0; e < 8; ++e) v[e] = f2bf(nw2[(kb + e)*128 + col]);
    G2[f] = v;
  }
  __syncthreads();

  const int wv = tid >> 6, lane = tid & 63;
  const int lo = lane & 15, hi = lane >> 4;
  short* m1w = &m1s[wv][0];

  float b1v[8], b2v[8], gv[8], bv[8];
  #pragma unroll
  for (int nf = 0; nf < 8; ++nf) {
    b1v[nf] = nb1[nf*16 + lo];
    b2v[nf] = nb2[nf*16 + lo];
    gv[nf]  = gam[nf*16 + lo];
    bv[nf]  = bet[nf*16 + lo];
  }
  const f32x4 zero4 = {0.f, 0.f, 0.f, 0.f};

  const int row0 = (blockIdx.x * 8 + wv) * 16;

  const float* hrow = h   + (size_t)(row0 + lo) * HID;
  const float* arow = agg + (size_t)(row0 + lo) * HID;
  const short* hbrow = hb + (size_t)(row0 + lo) * HID;

  f32x4 acc1[8];
  #pragma unroll
  for (int nf = 0; nf < 8; ++nf) acc1[nf] = zero4;
  #pragma unroll
  for (int kc = 0; kc < 8; ++kc) {
    short8 a;
    if (kc < 4) {
      if constexpr (HBF) a = *(const short8*)(hbrow + kc*32 + hi*8);
      else               a = cv8(hrow + kc*32 + hi*8);
    } else {
      a = cv8(arow + (kc - 4)*32 + hi*8);
    }
    #pragma unroll
    for (int nf = 0; nf < 8; ++nf) {
      short8 bf = G1[(kc*8 + nf)*64 + lane];
      acc1[nf] = __builtin_amdgcn_mfma_f32_16x16x32_bf16(a, bf, acc1[nf], 0,0,0);
    }
  }

  #pragma unroll
  for (int nf = 0; nf < 8; ++nf) {
    #pragma unroll
    for (int q = 0; q < 4; ++q) {
      float s = silu_f(acc1[nf][q] + b1v[nf]);
      int row = hi*4 + q, col = nf*16 + lo;
      int byteoff = ((row << 8) + (col << 1)) ^ ((row & 7) << 4);
      *(short*)((char*)m1w + byteoff) = f2bf(s);
    }
  }

  f32x4 acc2[8];
  #pragma unroll
  for (int nf = 0; nf < 8; ++nf) acc2[nf] = zero4;
  #pragma unroll
  for (int kc = 0; kc < 4; ++kc) {
    int byteA = ((lo << 8) + ((kc*32 + hi*8) << 1)) ^ ((lo & 7) << 4);
    short8 a = *(const short8*)((char*)m1w + byteA);
    #pragma unroll
    for (int nf = 0; nf < 8; ++nf) {
      short8 bf = G2[(kc*8 + nf)*64 + lane];
      acc2[nf] = __builtin_amdgcn_mfma_f32_16x16x32_bf16(a, bf, acc2[nf], 0,0,0);
    }
  }

  float xv[4][8];
  #pragma unroll
  for (int nf = 0; nf < 8; ++nf) {
    #pragma unroll
    for (int q = 0; q < 4; ++q) {
      xv[q][nf] = acc2[nf][q] + b2v[nf]
                + h[(size_t)(row0 + hi*4 + q) * HID + nf*16 + lo];
    }
  }

  #pragma unroll
  for (int q = 0; q < 4; ++q) {
    float s = 0.0f;
    #pragma unroll
    for (int nf = 0; nf < 8; ++nf) s += xv[q][nf];
    s += __shfl_xor(s, 1); s += __shfl_xor(s, 2);
    s += __shfl_xor(s, 4); s += __shfl_xor(s, 8);
    float mu = s * 0.0078125f;
    float t = 0.0f;
    #pragma unroll
    for (int nf = 0; nf < 8; ++nf) { float d = xv[q][nf] - mu; t += d * d; }
    t += __shfl_xor(t, 1); t += __shfl_xor(t, 2);
    t += __shfl_xor(t, 4); t += __shfl_xor(t, 8);
    float inv = 1.0f / sqrtf(t * 0.0078125f + 1e-5f);
    #pragma unroll
    for (int nf = 0; nf < 8; ++nf) {
      float y = (xv[q][nf] - mu) * inv * gv[nf] + bv[nf];
      out[(size_t)(row0 + hi*4 + q) * HID + nf*16 + lo] = y;
    }
  }
}

// ---------------------------------------------------------------------------
extern "C" void kernel_launch(void* const* d_in, const int* in_sizes, int n_in,
                              void* d_out, int out_size, void* d_ws, size_t ws_size,
                              hipStream_t stream) {
  (void)in_sizes; (void)n_in; (void)out_size;
  const float* h   = (const float*)d_in[0];
  const float* pos = (const float*)d_in[1];
  const float* ew1 = (const float*)d_in[2];
  const float* eb1 = (const float*)d_in[3];
  const float* ew2 = (const float*)d_in[4];
  const float* eb2 = (const float*)d_in[5];
  const float* nw1 = (const float*)d_in[6];
  const float* nb1 = (const float*)d_in[7];
  const float* nw2 = (const float*)d_in[8];
  const float* nb2 = (const float*)d_in[9];
  const float* gam = (const float*)d_in[10];
  const float* bet = (const float*)d_in[11];

  // ws: eidx 2MB | edist 2MB | hb(bf16 h) 8.4MB (optional). agg lives in d_out.
  const size_t base_need = (size_t)NBATCH * NNODE * KNN * 8;                 // 4 MB
  const size_t hbf_need  = base_need + (size_t)NBATCH * NNODE * HID * 2;     // +8.4 MB
  if (ws_size < base_need) return;
  const bool use_hbf = (ws_size >= hbf_need);

  char* wsp = (char*)d_ws;
  int*   eidx  = (int*)wsp;
  float* edist = (float*)(wsp + (size_t)NBATCH * NNODE * KNN * 4);
  short* hb    = (short*)(wsp + base_need);
  float* agg   = (float*)d_out;

  if (use_hbf) {
    hcvt_kernel<<<dim3(2048), dim3(256), 0, stream>>>(h, hb);
  }
  knn_kernel<<<dim3(1024), dim3(512), 0, stream>>>(pos, eidx, edist);
  if (use_hbf) {
    edge_kernel<true ><<<dim3(256), dim3(1024), 0, stream>>>(h, hb, eidx, edist,
                                                             ew1, eb1, ew2, eb2, agg);
    node_kernel<true ><<<dim3(256), dim3(512), 0, stream>>>(h, hb, agg, nw1, nb1,
                                                            nw2, nb2, gam, bet, (float*)d_out);
  } else {
    edge_kernel<false><<<dim3(256), dim3(1024), 0, stream>>>(h, hb, eidx, edist,
                                                             ew1, eb1, ew2, eb2, agg);
    node_kernel<false><<<dim3(256), dim3(512), 0, stream>>>(h, hb, agg, nw1, nb1,
                                                            nw2, nb2, gam, bet, (float*)d_out);
  }
}

// Round 11
// 241.623 us; speedup vs baseline: 1.0405x; 1.0046x over previous
//
#include <hip/hip_runtime.h>

#define HID 128
#define NRBF 20
#define KNN 16
#define NNODE 4096
#define NBATCH 8
#define CAP 112

typedef __attribute__((ext_vector_type(8))) short short8;
typedef __attribute__((ext_vector_type(4))) float f32x4;

// branchless RNE f32->bf16 (inputs finite here)
__device__ __forceinline__ short f2bf(float x) {
  unsigned u = __builtin_bit_cast(unsigned, x);
  u = u + 0x7FFFu + ((u >> 16) & 1u);
  return (short)(u >> 16);
}
__device__ __forceinline__ float silu_f(float x) {
  return x * __builtin_amdgcn_rcpf(1.0f + __expf(-x));  // ~1e-7 rel err << bf16 rounding
}
__device__ __forceinline__ short8 cv8(const float* p) {
  f32x4 a = *(const f32x4*)p;
  f32x4 b = *(const f32x4*)(p + 4);
  short8 r;
  r[0]=f2bf(a[0]); r[1]=f2bf(a[1]); r[2]=f2bf(a[2]); r[3]=f2bf(a[3]);
  r[4]=f2bf(b[0]); r[5]=f2bf(b[1]); r[6]=f2bf(b[2]); r[7]=f2bf(b[3]);
  return r;
}

// ---------------------------------------------------------------------------
// Kernel 0: h (f32) -> hb (bf16), once. BW-bound (~3-5 us).
// ---------------------------------------------------------------------------
__global__ __launch_bounds__(256)
void hcvt_kernel(const float* __restrict__ h, short* __restrict__ hb)
{
  size_t i = ((size_t)blockIdx.x * 256 + threadIdx.x) * 8;
  *(short8*)(hb + i) = cv8(h + i);
}

// ---------------------------------------------------------------------------
// Kernel 1: exact kNN (top-16, stable index tiebreak). (unchanged from R10)
// FMA fast-scan + inflated threshold; exact d2 recomputed for <=CAP
// candidates; exact stable rank selection -> set identical to numpy.
// ---------------------------------------------------------------------------
__global__ __launch_bounds__(512)
void knn_kernel(const float* __restrict__ pos,
                int* __restrict__ eidx, float* __restrict__ edist)
{
  __shared__ float pX[NNODE], pY[NNODE], pZ[NNODE];   // 48 KB
  __shared__ float d2b[8][4][CAP];                    // 14 KB
  __shared__ int   jb[8][4][CAP];                     // 14 KB
  __shared__ int   cntL[8][4];

  const int tid  = threadIdx.x;
  const int wv   = tid >> 6;
  const int lane = tid & 63;
  const int b    = blockIdx.x >> 7;
  const int grp  = blockIdx.x & 127;

  const float* pb = pos + (size_t)b * NNODE * 3;
  for (int idx = tid; idx < NNODE; idx += 512) {
    pX[idx] = pb[idx*3]; pY[idx] = pb[idx*3+1]; pZ[idx] = pb[idx*3+2];
  }
  __syncthreads();

  const int i0 = grp * 32 + wv * 4;
  float pix[4], piy[4], piz[4];
  #pragma unroll
  for (int n = 0; n < 4; ++n) { pix[n]=pX[i0+n]; piy[n]=pY[i0+n]; piz[n]=pZ[i0+n]; }

  float vmin[4] = {3.0e38f, 3.0e38f, 3.0e38f, 3.0e38f};
  #pragma unroll 4
  for (int t = 0; t < 64; ++t) {
    const int j = t * 64 + lane;
    const float x = pX[j], y = pY[j], z = pZ[j];
    #pragma unroll
    for (int n = 0; n < 4; ++n) {
      float dx = pix[n] - x, dy = piy[n] - y, dz = piz[n] - z;
      float d2 = fmaf(dz, dz, fmaf(dy, dy, dx * dx));
      vmin[n] = fminf(vmin[n], d2);
    }
  }

  float Tp[4];
  #pragma unroll
  for (int n = 0; n < 4; ++n) {
    float v = vmin[n];
    #pragma unroll
    for (int k = 2; k <= 64; k <<= 1) {
      #pragma unroll
      for (int jj = k >> 1; jj > 0; jj >>= 1) {
        float o = __shfl_xor(v, jj);
        const bool up   = ((lane & k) == 0);
        const bool lowl = ((lane & jj) == 0);
        float mn = fminf(v, o), mx = fmaxf(v, o);
        v = (up == lowl) ? mn : mx;
      }
    }
    float Tf = __shfl(v, 16);          // elem 16: >= 16th non-self FAST dist
    Tp[n] = Tf * (1.0f + 2.0e-6f) + 1.0e-35f;  // covers fast<->exact skew
  }

  if (lane < 4) cntL[wv][lane] = 0;
  #pragma unroll 2
  for (int t = 0; t < 64; ++t) {
    const int j = t * 64 + lane;
    const float x = pX[j], y = pY[j], z = pZ[j];
    #pragma unroll
    for (int n = 0; n < 4; ++n) {
      float dx = pix[n] - x, dy = piy[n] - y, dz = piz[n] - z;
      float d2 = fmaf(dz, dz, fmaf(dy, dy, dx * dx));
      if ((j != i0 + n) && (d2 <= Tp[n])) {
        int p = atomicAdd(&cntL[wv][n], 1);
        if (p < CAP) jb[wv][n][p] = j;
      }
    }
  }

  #pragma unroll 1
  for (int n = 0; n < 4; ++n) {
    int cnt = cntL[wv][n];
    if (cnt > CAP) cnt = CAP;
    for (int s = lane; s < cnt; s += 64) {
      int j = jb[wv][n][s];
      float dx = __fsub_rn(pix[n], pX[j]);
      float dy = __fsub_rn(piy[n], pY[j]);
      float dz = __fsub_rn(piz[n], pZ[j]);
      d2b[wv][n][s] = __fadd_rn(__fadd_rn(__fmul_rn(dx,dx), __fmul_rn(dy,dy)),
                                __fmul_rn(dz,dz));
    }
    for (int s = lane; s < cnt; s += 64) {
      float dm = d2b[wv][n][s]; int jm = jb[wv][n][s];
      int rank = 0;
      for (int c = 0; c < cnt; ++c) {
        float dc = d2b[wv][n][c]; int jc = jb[wv][n][c];
        if (dc < dm || (dc == dm && jc < jm)) ++rank;
      }
      if (rank < KNN) {
        size_t base = ((size_t)b * NNODE + i0 + n) * KNN;
        eidx[base + rank]  = b * NNODE + jm;
        edist[base + rank] = sqrtf(__fadd_rn(dm, 1e-8f));
      }
    }
  }
}

// ---------------------------------------------------------------------------
// Kernel 2: edge MLP + mask + aggregate.
// 1024-thread/16-wave blocks = 4 waves/SIMD. amdgpu_waves_per_eu(4,4) PINS
// the allocator target at 4 waves/EU -> 128-VGPR budget (body needs ~116).
// R9/R10 failed because launch_bounds' 2nd arg is only a *minimum* waves/EU;
// the heuristic still targeted 8/EU -> 64 regs -> 171 MB of spill writes.
// ---------------------------------------------------------------------------
#define ENPW 8

template<bool HBF>
__global__ __launch_bounds__(1024)
__attribute__((amdgpu_waves_per_eu(4, 4)))
void edge_kernel(const float* __restrict__ h, const short* __restrict__ hb,
                 const int* __restrict__ eidx, const float* __restrict__ edist,
                 const float* __restrict__ ew1, const float* __restrict__ eb1,
                 const float* __restrict__ ew2, const float* __restrict__ eb2,
                 float* __restrict__ agg)
{
  __shared__ __attribute__((aligned(16))) short8 F1[9*8*64];   // 73,728 B
  __shared__ __attribute__((aligned(16))) short8 F2[4*8*64];   // 32,768 B
  __shared__ __attribute__((aligned(16))) short m1s[16][1024]; // 32,768 B

  const int tid = threadIdx.x;
  for (int f = tid; f < 9*8*64; f += 1024) {
    int kc = f >> 9, rem = f & 511, nf = rem >> 6, ln = rem & 63;
    int kb = kc*32 + (ln >> 4)*8, col = nf*16 + (ln & 15);
    short8 v;
    #pragma unroll
    for (int e = 0; e < 8; ++e) {
      int k = kb + e;
      v[e] = (k < 276) ? f2bf(ew1[k*128 + col]) : (short)0;
    }
    F1[f] = v;
  }
  for (int f = tid; f < 4*8*64; f += 1024) {
    int kc = f >> 9, rem = f & 511, nf = rem >> 6, ln = rem & 63;
    int kb = kc*32 + (ln >> 4)*8, col = nf*16 + (ln & 15);
    short8 v;
    #pragma unroll
    for (int e = 0; e < 8; ++e) v[e] = f2bf(ew2[(kb + e)*128 + col]);
    F2[f] = v;
  }
  __syncthreads();

  const int wv = tid >> 6, lane = tid & 63;
  const int lo = lane & 15, hi = lane >> 4;
  short* m1w = &m1s[wv][0];

  float b1v[8], b2v[8];
  #pragma unroll
  for (int nf = 0; nf < 8; ++nf) {
    b1v[nf] = eb1[nf*16 + lo];
    b2v[nf] = eb2[nf*16 + lo];
  }
  // half-col m1 addressing: [16 rows][64 cols] bf16, 16B slots 0..7/row
  int wrow[4], wkey[4], rb[2];
  #pragma unroll
  for (int q = 0; q < 4; ++q) {
    int row = hi*4 + q;
    wrow[q] = row << 7;
    wkey[q] = row & 7;
  }
  const int inb = (lo & 7) << 1;
  const int slotb0 = (lo >> 3);      // + nfl*2
  #pragma unroll
  for (int kcl = 0; kcl < 2; ++kcl)
    rb[kcl] = (lo << 7) + (((kcl*4 + hi) ^ (lo & 7)) << 4);

  const f32x4 zero4 = {0.f, 0.f, 0.f, 0.f};
  const int nbase = (blockIdx.x * 16 + wv) * ENPW;

  #pragma unroll 1
  for (int it = 0; it < ENPW/2; ++it) {
    const int nA = nbase + it*2, nB = nA + 1;
    int jgA = eidx[(size_t)nA*KNN + lo] & (NBATCH*NNODE - 1);
    int jgB = eidx[(size_t)nB*KNN + lo] & (NBATCH*NNODE - 1);
    const float deA = edist[(size_t)nA*KNN + lo];
    const float deB = edist[(size_t)nB*KNN + lo];

    short8 aIA[4], aJA[4], aIB[4], aJB[4];
    #pragma unroll
    for (int kc = 0; kc < 4; ++kc) {
      if constexpr (HBF) {
        aIA[kc] = *(const short8*)(hb + (size_t)nA*HID  + kc*32 + hi*8);
        aJA[kc] = *(const short8*)(hb + (size_t)jgA*HID + kc*32 + hi*8);
        aIB[kc] = *(const short8*)(hb + (size_t)nB*HID  + kc*32 + hi*8);
        aJB[kc] = *(const short8*)(hb + (size_t)jgB*HID + kc*32 + hi*8);
      } else {
        aIA[kc] = cv8(h + (size_t)nA*HID  + kc*32 + hi*8);
        aJA[kc] = cv8(h + (size_t)jgA*HID + kc*32 + hi*8);
        aIB[kc] = cv8(h + (size_t)nB*HID  + kc*32 + hi*8);
        aJB[kc] = cv8(h + (size_t)jgB*HID + kc*32 + hi*8);
      }
    }
    short8 aRA, aRB;
    #pragma unroll
    for (int e = 0; e < 8; ++e) {
      const int r = hi*8 + e;
      float vA = 0.f, vB = 0.f;
      if (r < NRBF) {
        const float cr = (float)(r * (5.0/19.0));
        float tA = __fsub_rn(deA, cr), tB = __fsub_rn(deB, cr);
        vA = __expf(-16.0f * __fmul_rn(tA, tA));
        vB = __expf(-16.0f * __fmul_rn(tB, tB));
      }
      aRA[e] = f2bf(vA); aRB[e] = f2bf(vB);
    }

    f32x4 acc1A[8], acc1B[8];
    #pragma unroll
    for (int nf = 0; nf < 8; ++nf) { acc1A[nf] = zero4; acc1B[nf] = zero4; }
    __builtin_amdgcn_s_setprio(1);
    #pragma unroll
    for (int kc = 0; kc < 9; ++kc) {
      short8 aA = (kc < 4) ? aIA[kc] : ((kc < 8) ? aJA[kc-4] : aRA);
      short8 aB = (kc < 4) ? aIB[kc] : ((kc < 8) ? aJB[kc-4] : aRB);
      #pragma unroll
      for (int nf = 0; nf < 8; ++nf) {
        short8 bf = F1[(kc*8 + nf)*64 + lane];     // one read feeds 2 MFMAs
        acc1A[nf] = __builtin_amdgcn_mfma_f32_16x16x32_bf16(aA, bf, acc1A[nf], 0,0,0);
        acc1B[nf] = __builtin_amdgcn_mfma_f32_16x16x32_bf16(aB, bf, acc1B[nf], 0,0,0);
      }
    }
    __builtin_amdgcn_s_setprio(0);

    // m1 transpose through per-wave [16][64] buffer, two col-halves per node.
    short8 a2A[4], a2B[4];
    #pragma unroll
    for (int hh = 0; hh < 2; ++hh) {
      #pragma unroll
      for (int nfl = 0; nfl < 4; ++nfl) {
        int nf = hh*4 + nfl;
        int slot = nfl*2 + slotb0;
        #pragma unroll
        for (int q = 0; q < 4; ++q) {
          float s = silu_f(acc1A[nf][q] + b1v[nf]);
          int off = wrow[q] + ((slot ^ wkey[q]) << 4) + inb;
          *(short*)((char*)m1w + off) = f2bf(s);
        }
      }
      #pragma unroll
      for (int kcl = 0; kcl < 2; ++kcl)
        a2A[hh*2 + kcl] = *(const short8*)((char*)m1w + rb[kcl]);
    }
    #pragma unroll
    for (int hh = 0; hh < 2; ++hh) {
      #pragma unroll
      for (int nfl = 0; nfl < 4; ++nfl) {
        int nf = hh*4 + nfl;
        int slot = nfl*2 + slotb0;
        #pragma unroll
        for (int q = 0; q < 4; ++q) {
          float s = silu_f(acc1B[nf][q] + b1v[nf]);
          int off = wrow[q] + ((slot ^ wkey[q]) << 4) + inb;
          *(short*)((char*)m1w + off) = f2bf(s);
        }
      }
      #pragma unroll
      for (int kcl = 0; kcl < 2; ++kcl)
        a2B[hh*2 + kcl] = *(const short8*)((char*)m1w + rb[kcl]);
    }

    f32x4 acc2A[8], acc2B[8];
    #pragma unroll
    for (int nf = 0; nf < 8; ++nf) { acc2A[nf] = zero4; acc2B[nf] = zero4; }
    __builtin_amdgcn_s_setprio(1);
    #pragma unroll
    for (int kc = 0; kc < 4; ++kc) {
      #pragma unroll
      for (int nf = 0; nf < 8; ++nf) {
        short8 bf = F2[(kc*8 + nf)*64 + lane];
        acc2A[nf] = __builtin_amdgcn_mfma_f32_16x16x32_bf16(a2A[kc], bf, acc2A[nf], 0,0,0);
        acc2B[nf] = __builtin_amdgcn_mfma_f32_16x16x32_bf16(a2B[kc], bf, acc2B[nf], 0,0,0);
      }
    }
    __builtin_amdgcn_s_setprio(0);

    float dqA[4], dqB[4];
    #pragma unroll
    for (int q = 0; q < 4; ++q) {
      dqA[q] = __shfl(deA, hi*4 + q);   // lane s<16 holds edist[node*16+s]
      dqB[q] = __shfl(deB, hi*4 + q);
    }
    #pragma unroll
    for (int nf = 0; nf < 8; ++nf) {
      float sA = 0.f, sB = 0.f;
      #pragma unroll
      for (int q = 0; q < 4; ++q) {
        float mA = silu_f(acc2A[nf][q] + b2v[nf]);
        float mB = silu_f(acc2B[nf][q] + b2v[nf]);
        sA += (dqA[q] < 5.0f) ? mA : 0.f;
        sB += (dqB[q] < 5.0f) ? mB : 0.f;
      }
      sA += __shfl_xor(sA, 16); sA += __shfl_xor(sA, 32);
      sB += __shfl_xor(sB, 16); sB += __shfl_xor(sB, 32);
      if (hi == 0) {
        agg[(size_t)nA*HID + nf*16 + lo] = sA;
        agg[(size_t)nB*HID + nf*16 + lo] = sB;
      }
    }
  }
}

// ---------------------------------------------------------------------------
// Kernel 3: node MLP + residual + LayerNorm, agg==out in-place. (unchanged)
// ---------------------------------------------------------------------------
template<bool HBF>
__global__ __launch_bounds__(512)
void node_kernel(const float* __restrict__ h, const short* __restrict__ hb,
                 const float* agg,
                 const float* __restrict__ nw1, const float* __restrict__ nb1,
                 const float* __restrict__ nw2, const float* __restrict__ nb2,
                 const float* __restrict__ gam, const float* __restrict__ bet,
                 float* out)
{
  __shared__ __attribute__((aligned(16))) short8 G1[8*8*64];   // 65,536 B
  __shared__ __attribute__((aligned(16))) short8 G2[4*8*64];   // 32,768 B
  __shared__ __attribute__((aligned(16))) short m1s[8][2048];  // 32,768 B

  const int tid = threadIdx.x;
  for (int f = tid; f < 8*8*64; f += 512) {
    int kc = f >> 9, rem = f & 511, nf = rem >> 6, ln = rem & 63;
    int kb = kc*32 + (ln >> 4)*8, col = nf*16 + (ln & 15);
    short8 v;
    #pragma unroll
    for (int e = 0; e < 8; ++e) v[e] = f2bf(nw1[(kb + e)*128 + col]);
    G1[f] = v;
  }
  for (int f = tid; f < 4*8*64; f += 512) {
    int kc = f >> 9, rem = f & 511, nf = rem >> 6, ln = rem & 63;
    int kb = kc*32 + (ln >> 4)*8, col = nf*16 + (ln & 15);
    short8 v;
    #pragma unroll
    for (int e = 0; e < 8; ++e) v[e] = f2bf(nw2[(kb + e)*128 + col]);
    G2[f] = v;
  }
  __syncthreads();

  const int wv = tid >> 6, lane = tid & 63;
  const int lo = lane & 15, hi = lane >> 4;
  short* m1w = &m1s[wv][0];

  float b1v[8], b2v[8], gv[8], bv[8];
  #pragma unroll
  for (int nf = 0; nf < 8; ++nf) {
    b1v[nf] = nb1[nf*16 + lo];
    b2v[nf] = nb2[nf*16 + lo];
    gv[nf]  = gam[nf*16 + lo];
    bv[nf]  = bet[nf*16 + lo];
  }
  const f32x4 zero4 = {0.f, 0.f, 0.f, 0.f};

  const int row0 = (blockIdx.x * 8 + wv) * 16;

  const float* hrow = h   + (size_t)(row0 + lo) * HID;
  const float* arow = agg + (size_t)(row0 + lo) * HID;
  const short* hbrow = hb + (size_t)(row0 + lo) * HID;

  f32x4 acc1[8];
  #pragma unroll
  for (int nf = 0; nf < 8; ++nf) acc1[nf] = zero4;
  #pragma unroll
  for (int kc = 0; kc < 8; ++kc) {
    short8 a;
    if (kc < 4) {
      if constexpr (HBF) a = *(const short8*)(hbrow + kc*32 + hi*8);
      else               a = cv8(hrow + kc*32 + hi*8);
    } else {
      a = cv8(arow + (kc - 4)*32 + hi*8);
    }
    #pragma unroll
    for (int nf = 0; nf < 8; ++nf) {
      short8 bf = G1[(kc*8 + nf)*64 + lane];
      acc1[nf] = __builtin_amdgcn_mfma_f32_16x16x32_bf16(a, bf, acc1[nf], 0,0,0);
    }
  }

  #pragma unroll
  for (int nf = 0; nf < 8; ++nf) {
    #pragma unroll
    for (int q = 0; q < 4; ++q) {
      float s = silu_f(acc1[nf][q] + b1v[nf]);
      int row = hi*4 + q, col = nf*16 + lo;
      int byteoff = ((row << 8) + (col << 1)) ^ ((row & 7) << 4);
      *(short*)((char*)m1w + byteoff) = f2bf(s);
    }
  }

  f32x4 acc2[8];
  #pragma unroll
  for (int nf = 0; nf < 8; ++nf) acc2[nf] = zero4;
  #pragma unroll
  for (int kc = 0; kc < 4; ++kc) {
    int byteA = ((lo << 8) + ((kc*32 + hi*8) << 1)) ^ ((lo & 7) << 4);
    short8 a = *(const short8*)((char*)m1w + byteA);
    #pragma unroll
    for (int nf = 0; nf < 8; ++nf) {
      short8 bf = G2[(kc*8 + nf)*64 + lane];
      acc2[nf] = __builtin_amdgcn_mfma_f32_16x16x32_bf16(a, bf, acc2[nf], 0,0,0);
    }
  }

  float xv[4][8];
  #pragma unroll
  for (int nf = 0; nf < 8; ++nf) {
    #pragma unroll
    for (int q = 0; q < 4; ++q) {
      xv[q][nf] = acc2[nf][q] + b2v[nf]
                + h[(size_t)(row0 + hi*4 + q) * HID + nf*16 + lo];
    }
  }

  #pragma unroll
  for (int q = 0; q < 4; ++q) {
    float s = 0.0f;
    #pragma unroll
    for (int nf = 0; nf < 8; ++nf) s += xv[q][nf];
    s += __shfl_xor(s, 1); s += __shfl_xor(s, 2);
    s += __shfl_xor(s, 4); s += __shfl_xor(s, 8);
    float mu = s * 0.0078125f;
    float t = 0.0f;
    #pragma unroll
    for (int nf = 0; nf < 8; ++nf) { float d = xv[q][nf] - mu; t += d * d; }
    t += __shfl_xor(t, 1); t += __shfl_xor(t, 2);
    t += __shfl_xor(t, 4); t += __shfl_xor(t, 8);
    float inv = 1.0f / sqrtf(t * 0.0078125f + 1e-5f);
    #pragma unroll
    for (int nf = 0; nf < 8; ++nf) {
      float y = (xv[q][nf] - mu) * inv * gv[nf] + bv[nf];
      out[(size_t)(row0 + hi*4 + q) * HID + nf*16 + lo] = y;
    }
  }
}

// ---------------------------------------------------------------------------
extern "C" void kernel_launch(void* const* d_in, const int* in_sizes, int n_in,
                              void* d_out, int out_size, void* d_ws, size_t ws_size,
                              hipStream_t stream) {
  (void)in_sizes; (void)n_in; (void)out_size;
  const float* h   = (const float*)d_in[0];
  const float* pos = (const float*)d_in[1];
  const float* ew1 = (const float*)d_in[2];
  const float* eb1 = (const float*)d_in[3];
  const float* ew2 = (const float*)d_in[4];
  const float* eb2 = (const float*)d_in[5];
  const float* nw1 = (const float*)d_in[6];
  const float* nb1 = (const float*)d_in[7];
  const float* nw2 = (const float*)d_in[8];
  const float* nb2 = (const float*)d_in[9];
  const float* gam = (const float*)d_in[10];
  const float* bet = (const float*)d_in[11];

  // ws: eidx 2MB | edist 2MB | hb(bf16 h) 8.4MB (optional). agg lives in d_out.
  const size_t base_need = (size_t)NBATCH * NNODE * KNN * 8;                 // 4 MB
  const size_t hbf_need  = base_need + (size_t)NBATCH * NNODE * HID * 2;     // +8.4 MB
  if (ws_size < base_need) return;
  const bool use_hbf = (ws_size >= hbf_need);

  char* wsp = (char*)d_ws;
  int*   eidx  = (int*)wsp;
  float* edist = (float*)(wsp + (size_t)NBATCH * NNODE * KNN * 4);
  short* hb    = (short*)(wsp + base_need);
  float* agg   = (float*)d_out;

  if (use_hbf) {
    hcvt_kernel<<<dim3(2048), dim3(256), 0, stream>>>(h, hb);
  }
  knn_kernel<<<dim3(1024), dim3(512), 0, stream>>>(pos, eidx, edist);
  if (use_hbf) {
    edge_kernel<true ><<<dim3(256), dim3(1024), 0, stream>>>(h, hb, eidx, edist,
                                                             ew1, eb1, ew2, eb2, agg);
    node_kernel<true ><<<dim3(256), dim3(512), 0, stream>>>(h, hb, agg, nw1, nb1,
                                                            nw2, nb2, gam, bet, (float*)d_out);
  } else {
    edge_kernel<false><<<dim3(256), dim3(1024), 0, stream>>>(h, hb, eidx, edist,
                                                             ew1, eb1, ew2, eb2, agg);
    node_kernel<false><<<dim3(256), dim3(512), 0, stream>>>(h, hb, agg, nw1, nb1,
                                                            nw2, nb2, gam, bet, (float*)d_out);
  }
}

// Round 12
// 203.546 us; speedup vs baseline: 1.2352x; 1.1871x over previous
//
#include <hip/hip_runtime.h>

#define HID 128
#define NRBF 20
#define KNN 16
#define NNODE 4096
#define NBATCH 8
#define CAP 112

typedef __attribute__((ext_vector_type(8))) short short8;
typedef __attribute__((ext_vector_type(4))) float f32x4;

// branchless RNE f32->bf16 (inputs finite here)
__device__ __forceinline__ short f2bf(float x) {
  unsigned u = __builtin_bit_cast(unsigned, x);
  u = u + 0x7FFFu + ((u >> 16) & 1u);
  return (short)(u >> 16);
}
__device__ __forceinline__ float silu_f(float x) {
  return x * __builtin_amdgcn_rcpf(1.0f + __expf(-x));  // ~1e-7 rel err << bf16 rounding
}
__device__ __forceinline__ short8 cv8(const float* p) {
  f32x4 a = *(const f32x4*)p;
  f32x4 b = *(const f32x4*)(p + 4);
  short8 r;
  r[0]=f2bf(a[0]); r[1]=f2bf(a[1]); r[2]=f2bf(a[2]); r[3]=f2bf(a[3]);
  r[4]=f2bf(b[0]); r[5]=f2bf(b[1]); r[6]=f2bf(b[2]); r[7]=f2bf(b[3]);
  return r;
}

// ---------------------------------------------------------------------------
// Kernel 0: h (f32) -> hb (bf16), once. BW-bound (~3-5 us).
// ---------------------------------------------------------------------------
__global__ __launch_bounds__(256)
void hcvt_kernel(const float* __restrict__ h, short* __restrict__ hb)
{
  size_t i = ((size_t)blockIdx.x * 256 + threadIdx.x) * 8;
  *(short8*)(hb + i) = cv8(h + i);
}

// ---------------------------------------------------------------------------
// Kernel 1: exact kNN (top-16, stable index tiebreak).
// FMA fast-scan + inflated threshold; exact d2 recomputed for <=CAP
// candidates; exact stable rank selection -> set identical to numpy.
// ---------------------------------------------------------------------------
__global__ __launch_bounds__(512)
void knn_kernel(const float* __restrict__ pos,
                int* __restrict__ eidx, float* __restrict__ edist)
{
  __shared__ float pX[NNODE], pY[NNODE], pZ[NNODE];   // 48 KB
  __shared__ float d2b[8][4][CAP];                    // 14 KB
  __shared__ int   jb[8][4][CAP];                     // 14 KB
  __shared__ int   cntL[8][4];

  const int tid  = threadIdx.x;
  const int wv   = tid >> 6;
  const int lane = tid & 63;
  const int b    = blockIdx.x >> 7;
  const int grp  = blockIdx.x & 127;

  const float* pb = pos + (size_t)b * NNODE * 3;
  for (int idx = tid; idx < NNODE; idx += 512) {
    pX[idx] = pb[idx*3]; pY[idx] = pb[idx*3+1]; pZ[idx] = pb[idx*3+2];
  }
  __syncthreads();

  const int i0 = grp * 32 + wv * 4;
  float pix[4], piy[4], piz[4];
  #pragma unroll
  for (int n = 0; n < 4; ++n) { pix[n]=pX[i0+n]; piy[n]=pY[i0+n]; piz[n]=pZ[i0+n]; }

  // pass 1: per-lane strip minima of FAST d2 (self included, =0 exactly)
  float vmin[4] = {3.0e38f, 3.0e38f, 3.0e38f, 3.0e38f};
  #pragma unroll 4
  for (int t = 0; t < 64; ++t) {
    const int j = t * 64 + lane;
    const float x = pX[j], y = pY[j], z = pZ[j];
    #pragma unroll
    for (int n = 0; n < 4; ++n) {
      float dx = pix[n] - x, dy = piy[n] - y, dz = piz[n] - z;
      float d2 = fmaf(dz, dz, fmaf(dy, dy, dx * dx));
      vmin[n] = fminf(vmin[n], d2);
    }
  }

  float Tp[4];
  #pragma unroll
  for (int n = 0; n < 4; ++n) {
    float v = vmin[n];
    #pragma unroll
    for (int k = 2; k <= 64; k <<= 1) {
      #pragma unroll
      for (int jj = k >> 1; jj > 0; jj >>= 1) {
        float o = __shfl_xor(v, jj);
        const bool up   = ((lane & k) == 0);
        const bool lowl = ((lane & jj) == 0);
        float mn = fminf(v, o), mx = fmaxf(v, o);
        v = (up == lowl) ? mn : mx;
      }
    }
    float Tf = __shfl(v, 16);          // elem 16: >= 16th non-self FAST dist
    Tp[n] = Tf * (1.0f + 2.0e-6f) + 1.0e-35f;  // covers fast<->exact skew
  }

  if (lane < 4) cntL[wv][lane] = 0;
  // pass 2: ONE batched FAST scan, compact indices only
  #pragma unroll 2
  for (int t = 0; t < 64; ++t) {
    const int j = t * 64 + lane;
    const float x = pX[j], y = pY[j], z = pZ[j];
    #pragma unroll
    for (int n = 0; n < 4; ++n) {
      float dx = pix[n] - x, dy = piy[n] - y, dz = piz[n] - z;
      float d2 = fmaf(dz, dz, fmaf(dy, dy, dx * dx));
      if ((j != i0 + n) && (d2 <= Tp[n])) {
        int p = atomicAdd(&cntL[wv][n], 1);
        if (p < CAP) jb[wv][n][p] = j;
      }
    }
  }

  // recompute EXACT d2 for compacted candidates, then exact stable selection
  #pragma unroll 1
  for (int n = 0; n < 4; ++n) {
    int cnt = cntL[wv][n];
    if (cnt > CAP) cnt = CAP;
    for (int s = lane; s < cnt; s += 64) {
      int j = jb[wv][n][s];
      float dx = __fsub_rn(pix[n], pX[j]);
      float dy = __fsub_rn(piy[n], pY[j]);
      float dz = __fsub_rn(piz[n], pZ[j]);
      d2b[wv][n][s] = __fadd_rn(__fadd_rn(__fmul_rn(dx,dx), __fmul_rn(dy,dy)),
                                __fmul_rn(dz,dz));
    }
    for (int s = lane; s < cnt; s += 64) {
      float dm = d2b[wv][n][s]; int jm = jb[wv][n][s];
      int rank = 0;
      for (int c = 0; c < cnt; ++c) {
        float dc = d2b[wv][n][c]; int jc = jb[wv][n][c];
        if (dc < dm || (dc == dm && jc < jm)) ++rank;
      }
      if (rank < KNN) {
        size_t base = ((size_t)b * NNODE + i0 + n) * KNN;
        eidx[base + rank]  = b * NNODE + jm;
        edist[base + rank] = sqrtf(__fadd_rn(dm, 1e-8f));
      }
    }
  }
}

// ---------------------------------------------------------------------------
// Kernel 2: edge MLP + mask + aggregate — R8's PROVEN shape:
// 512-thread/8-wave blocks, 1 block/CU, VGPR ~116 natural (no spills),
// ILP-2, fragment-linear weight LDS, single reused per-wave m1 buffer.
// (1024-thread variants spill: allocator pins 64-reg target; R9-R11 evidence.)
// ---------------------------------------------------------------------------
#define ENPW 16

template<bool HBF>
__global__ __launch_bounds__(512)
void edge_kernel(const float* __restrict__ h, const short* __restrict__ hb,
                 const int* __restrict__ eidx, const float* __restrict__ edist,
                 const float* __restrict__ ew1, const float* __restrict__ eb1,
                 const float* __restrict__ ew2, const float* __restrict__ eb2,
                 float* __restrict__ agg)
{
  __shared__ __attribute__((aligned(16))) short8 F1[9*8*64];   // 73,728 B
  __shared__ __attribute__((aligned(16))) short8 F2[4*8*64];   // 32,768 B
  __shared__ __attribute__((aligned(16))) short m1s[8][2048];  // 32,768 B

  const int tid = threadIdx.x;
  for (int f = tid; f < 9*8*64; f += 512) {
    int kc = f >> 9, rem = f & 511, nf = rem >> 6, ln = rem & 63;
    int kb = kc*32 + (ln >> 4)*8, col = nf*16 + (ln & 15);
    short8 v;
    #pragma unroll
    for (int e = 0; e < 8; ++e) {
      int k = kb + e;
      v[e] = (k < 276) ? f2bf(ew1[k*128 + col]) : (short)0;
    }
    F1[f] = v;
  }
  for (int f = tid; f < 4*8*64; f += 512) {
    int kc = f >> 9, rem = f & 511, nf = rem >> 6, ln = rem & 63;
    int kb = kc*32 + (ln >> 4)*8, col = nf*16 + (ln & 15);
    short8 v;
    #pragma unroll
    for (int e = 0; e < 8; ++e) v[e] = f2bf(ew2[(kb + e)*128 + col]);
    F2[f] = v;
  }
  __syncthreads();

  const int wv = tid >> 6, lane = tid & 63;
  const int lo = lane & 15, hi = lane >> 4;
  short* m1w = &m1s[wv][0];

  float b1v[8], b2v[8];
  #pragma unroll
  for (int nf = 0; nf < 8; ++nf) {
    b1v[nf] = eb1[nf*16 + lo];
    b2v[nf] = eb2[nf*16 + lo];
  }
  int wbase[4], xmask[4], rbase[4];
  #pragma unroll
  for (int q = 0; q < 4; ++q) {
    int row = hi*4 + q;
    wbase[q] = (row << 8) + (lo << 1);
    xmask[q] = (row & 7) << 4;
  }
  #pragma unroll
  for (int kc = 0; kc < 4; ++kc)
    rbase[kc] = ((lo << 8) + ((kc*32 + hi*8) << 1)) ^ ((lo & 7) << 4);

  const f32x4 zero4 = {0.f, 0.f, 0.f, 0.f};
  const int nbase = (blockIdx.x * 8 + wv) * ENPW;

  #pragma unroll 1
  for (int it = 0; it < ENPW/2; ++it) {
    const int nA = nbase + it*2, nB = nA + 1;
    int jgA = eidx[(size_t)nA*KNN + lo] & (NBATCH*NNODE - 1);
    int jgB = eidx[(size_t)nB*KNN + lo] & (NBATCH*NNODE - 1);
    const float deA = edist[(size_t)nA*KNN + lo];
    const float deB = edist[(size_t)nB*KNN + lo];

    short8 aIA[4], aJA[4], aIB[4], aJB[4];
    #pragma unroll
    for (int kc = 0; kc < 4; ++kc) {
      if constexpr (HBF) {
        aIA[kc] = *(const short8*)(hb + (size_t)nA*HID  + kc*32 + hi*8);
        aJA[kc] = *(const short8*)(hb + (size_t)jgA*HID + kc*32 + hi*8);
        aIB[kc] = *(const short8*)(hb + (size_t)nB*HID  + kc*32 + hi*8);
        aJB[kc] = *(const short8*)(hb + (size_t)jgB*HID + kc*32 + hi*8);
      } else {
        aIA[kc] = cv8(h + (size_t)nA*HID  + kc*32 + hi*8);
        aJA[kc] = cv8(h + (size_t)jgA*HID + kc*32 + hi*8);
        aIB[kc] = cv8(h + (size_t)nB*HID  + kc*32 + hi*8);
        aJB[kc] = cv8(h + (size_t)jgB*HID + kc*32 + hi*8);
      }
    }
    short8 aRA, aRB;
    #pragma unroll
    for (int e = 0; e < 8; ++e) {
      const int r = hi*8 + e;
      float vA = 0.f, vB = 0.f;
      if (r < NRBF) {
        const float cr = (float)(r * (5.0/19.0));
        float tA = __fsub_rn(deA, cr), tB = __fsub_rn(deB, cr);
        vA = __expf(-16.0f * __fmul_rn(tA, tA));
        vB = __expf(-16.0f * __fmul_rn(tB, tB));
      }
      aRA[e] = f2bf(vA); aRB[e] = f2bf(vB);
    }

    f32x4 acc1A[8], acc1B[8];
    #pragma unroll
    for (int nf = 0; nf < 8; ++nf) { acc1A[nf] = zero4; acc1B[nf] = zero4; }
    __builtin_amdgcn_s_setprio(1);
    #pragma unroll
    for (int kc = 0; kc < 9; ++kc) {
      short8 aA = (kc < 4) ? aIA[kc] : ((kc < 8) ? aJA[kc-4] : aRA);
      short8 aB = (kc < 4) ? aIB[kc] : ((kc < 8) ? aJB[kc-4] : aRB);
      #pragma unroll
      for (int nf = 0; nf < 8; ++nf) {
        short8 bf = F1[(kc*8 + nf)*64 + lane];     // one read feeds 2 MFMAs
        acc1A[nf] = __builtin_amdgcn_mfma_f32_16x16x32_bf16(aA, bf, acc1A[nf], 0,0,0);
        acc1B[nf] = __builtin_amdgcn_mfma_f32_16x16x32_bf16(aB, bf, acc1B[nf], 0,0,0);
      }
    }
    __builtin_amdgcn_s_setprio(0);

    // m1 transpose through ONE per-wave buffer (same-wave DS ordering)
    short8 a2A[4], a2B[4];
    #pragma unroll
    for (int nf = 0; nf < 8; ++nf) {
      #pragma unroll
      for (int q = 0; q < 4; ++q) {
        int off = (wbase[q] + (nf << 5)) ^ xmask[q];
        *(short*)((char*)m1w + off) = f2bf(silu_f(acc1A[nf][q] + b1v[nf]));
      }
    }
    #pragma unroll
    for (int kc = 0; kc < 4; ++kc)
      a2A[kc] = *(const short8*)((char*)m1w + rbase[kc]);
    #pragma unroll
    for (int nf = 0; nf < 8; ++nf) {
      #pragma unroll
      for (int q = 0; q < 4; ++q) {
        int off = (wbase[q] + (nf << 5)) ^ xmask[q];
        *(short*)((char*)m1w + off) = f2bf(silu_f(acc1B[nf][q] + b1v[nf]));
      }
    }
    #pragma unroll
    for (int kc = 0; kc < 4; ++kc)
      a2B[kc] = *(const short8*)((char*)m1w + rbase[kc]);

    f32x4 acc2A[8], acc2B[8];
    #pragma unroll
    for (int nf = 0; nf < 8; ++nf) { acc2A[nf] = zero4; acc2B[nf] = zero4; }
    __builtin_amdgcn_s_setprio(1);
    #pragma unroll
    for (int kc = 0; kc < 4; ++kc) {
      #pragma unroll
      for (int nf = 0; nf < 8; ++nf) {
        short8 bf = F2[(kc*8 + nf)*64 + lane];
        acc2A[nf] = __builtin_amdgcn_mfma_f32_16x16x32_bf16(a2A[kc], bf, acc2A[nf], 0,0,0);
        acc2B[nf] = __builtin_amdgcn_mfma_f32_16x16x32_bf16(a2B[kc], bf, acc2B[nf], 0,0,0);
      }
    }
    __builtin_amdgcn_s_setprio(0);

    float dqA[4], dqB[4];
    #pragma unroll
    for (int q = 0; q < 4; ++q) {
      dqA[q] = __shfl(deA, hi*4 + q);   // lane s<16 holds edist[node*16+s]
      dqB[q] = __shfl(deB, hi*4 + q);
    }
    #pragma unroll
    for (int nf = 0; nf < 8; ++nf) {
      float sA = 0.f, sB = 0.f;
      #pragma unroll
      for (int q = 0; q < 4; ++q) {
        float mA = silu_f(acc2A[nf][q] + b2v[nf]);
        float mB = silu_f(acc2B[nf][q] + b2v[nf]);
        sA += (dqA[q] < 5.0f) ? mA : 0.f;
        sB += (dqB[q] < 5.0f) ? mB : 0.f;
      }
      sA += __shfl_xor(sA, 16); sA += __shfl_xor(sA, 32);
      sB += __shfl_xor(sB, 16); sB += __shfl_xor(sB, 32);
      if (hi == 0) {
        agg[(size_t)nA*HID + nf*16 + lo] = sA;
        agg[(size_t)nB*HID + nf*16 + lo] = sB;
      }
    }
  }
}

// ---------------------------------------------------------------------------
// Kernel 3: node MLP + residual + LayerNorm, agg==out in-place. (unchanged)
// ---------------------------------------------------------------------------
template<bool HBF>
__global__ __launch_bounds__(512)
void node_kernel(const float* __restrict__ h, const short* __restrict__ hb,
                 const float* agg,
                 const float* __restrict__ nw1, const float* __restrict__ nb1,
                 const float* __restrict__ nw2, const float* __restrict__ nb2,
                 const float* __restrict__ gam, const float* __restrict__ bet,
                 float* out)
{
  __shared__ __attribute__((aligned(16))) short8 G1[8*8*64];   // 65,536 B
  __shared__ __attribute__((aligned(16))) short8 G2[4*8*64];   // 32,768 B
  __shared__ __attribute__((aligned(16))) short m1s[8][2048];  // 32,768 B

  const int tid = threadIdx.x;
  for (int f = tid; f < 8*8*64; f += 512) {
    int kc = f >> 9, rem = f & 511, nf = rem >> 6, ln = rem & 63;
    int kb = kc*32 + (ln >> 4)*8, col = nf*16 + (ln & 15);
    short8 v;
    #pragma unroll
    for (int e = 0; e < 8; ++e) v[e] = f2bf(nw1[(kb + e)*128 + col]);
    G1[f] = v;
  }
  for (int f = tid; f < 4*8*64; f += 512) {
    int kc = f >> 9, rem = f & 511, nf = rem >> 6, ln = rem & 63;
    int kb = kc*32 + (ln >> 4)*8, col = nf*16 + (ln & 15);
    short8 v;
    #pragma unroll
    for (int e = 0; e < 8; ++e) v[e] = f2bf(nw2[(kb + e)*128 + col]);
    G2[f] = v;
  }
  __syncthreads();

  const int wv = tid >> 6, lane = tid & 63;
  const int lo = lane & 15, hi = lane >> 4;
  short* m1w = &m1s[wv][0];

  float b1v[8], b2v[8], gv[8], bv[8];
  #pragma unroll
  for (int nf = 0; nf < 8; ++nf) {
    b1v[nf] = nb1[nf*16 + lo];
    b2v[nf] = nb2[nf*16 + lo];
    gv[nf]  = gam[nf*16 + lo];
    bv[nf]  = bet[nf*16 + lo];
  }
  const f32x4 zero4 = {0.f, 0.f, 0.f, 0.f};

  const int row0 = (blockIdx.x * 8 + wv) * 16;

  const float* hrow = h   + (size_t)(row0 + lo) * HID;
  const float* arow = agg + (size_t)(row0 + lo) * HID;
  const short* hbrow = hb + (size_t)(row0 + lo) * HID;

  f32x4 acc1[8];
  #pragma unroll
  for (int nf = 0; nf < 8; ++nf) acc1[nf] = zero4;
  #pragma unroll
  for (int kc = 0; kc < 8; ++kc) {
    short8 a;
    if (kc < 4) {
      if constexpr (HBF) a = *(const short8*)(hbrow + kc*32 + hi*8);
      else               a = cv8(hrow + kc*32 + hi*8);
    } else {
      a = cv8(arow + (kc - 4)*32 + hi*8);
    }
    #pragma unroll
    for (int nf = 0; nf < 8; ++nf) {
      short8 bf = G1[(kc*8 + nf)*64 + lane];
      acc1[nf] = __builtin_amdgcn_mfma_f32_16x16x32_bf16(a, bf, acc1[nf], 0,0,0);
    }
  }

  #pragma unroll
  for (int nf = 0; nf < 8; ++nf) {
    #pragma unroll
    for (int q = 0; q < 4; ++q) {
      float s = silu_f(acc1[nf][q] + b1v[nf]);
      int row = hi*4 + q, col = nf*16 + lo;
      int byteoff = ((row << 8) + (col << 1)) ^ ((row & 7) << 4);
      *(short*)((char*)m1w + byteoff) = f2bf(s);
    }
  }

  f32x4 acc2[8];
  #pragma unroll
  for (int nf = 0; nf < 8; ++nf) acc2[nf] = zero4;
  #pragma unroll
  for (int kc = 0; kc < 4; ++kc) {
    int byteA = ((lo << 8) + ((kc*32 + hi*8) << 1)) ^ ((lo & 7) << 4);
    short8 a = *(const short8*)((char*)m1w + byteA);
    #pragma unroll
    for (int nf = 0; nf < 8; ++nf) {
      short8 bf = G2[(kc*8 + nf)*64 + lane];
      acc2[nf] = __builtin_amdgcn_mfma_f32_16x16x32_bf16(a, bf, acc2[nf], 0,0,0);
    }
  }

  float xv[4][8];
  #pragma unroll
  for (int nf = 0; nf < 8; ++nf) {
    #pragma unroll
    for (int q = 0; q < 4; ++q) {
      xv[q][nf] = acc2[nf][q] + b2v[nf]
                + h[(size_t)(row0 + hi*4 + q) * HID + nf*16 + lo];
    }
  }

  #pragma unroll
  for (int q = 0; q < 4; ++q) {
    float s = 0.0f;
    #pragma unroll
    for (int nf = 0; nf < 8; ++nf) s += xv[q][nf];
    s += __shfl_xor(s, 1); s += __shfl_xor(s, 2);
    s += __shfl_xor(s, 4); s += __shfl_xor(s, 8);
    float mu = s * 0.0078125f;
    float t = 0.0f;
    #pragma unroll
    for (int nf = 0; nf < 8; ++nf) { float d = xv[q][nf] - mu; t += d * d; }
    t += __shfl_xor(t, 1); t += __shfl_xor(t, 2);
    t += __shfl_xor(t, 4); t += __shfl_xor(t, 8);
    float inv = 1.0f / sqrtf(t * 0.0078125f + 1e-5f);
    #pragma unroll
    for (int nf = 0; nf < 8; ++nf) {
      float y = (xv[q][nf] - mu) * inv * gv[nf] + bv[nf];
      out[(size_t)(row0 + hi*4 + q) * HID + nf*16 + lo] = y;
    }
  }
}

// ---------------------------------------------------------------------------
extern "C" void kernel_launch(void* const* d_in, const int* in_sizes, int n_in,
                              void* d_out, int out_size, void* d_ws, size_t ws_size,
                              hipStream_t stream) {
  (void)in_sizes; (void)n_in; (void)out_size;
  const float* h   = (const float*)d_in[0];
  const float* pos = (const float*)d_in[1];
  const float* ew1 = (const float*)d_in[2];
  const float* eb1 = (const float*)d_in[3];
  const float* ew2 = (const float*)d_in[4];
  const float* eb2 = (const float*)d_in[5];
  const float* nw1 = (const float*)d_in[6];
  const float* nb1 = (const float*)d_in[7];
  const float* nw2 = (const float*)d_in[8];
  const float* nb2 = (const float*)d_in[9];
  const float* gam = (const float*)d_in[10];
  const float* bet = (const float*)d_in[11];

  // ws: eidx 2MB | edist 2MB | hb(bf16 h) 8.4MB (optional). agg lives in d_out.
  const size_t base_need = (size_t)NBATCH * NNODE * KNN * 8;                 // 4 MB
  const size_t hbf_need  = base_need + (size_t)NBATCH * NNODE * HID * 2;     // +8.4 MB
  if (ws_size < base_need) return;
  const bool use_hbf = (ws_size >= hbf_need);

  char* wsp = (char*)d_ws;
  int*   eidx  = (int*)wsp;
  float* edist = (float*)(wsp + (size_t)NBATCH * NNODE * KNN * 4);
  short* hb    = (short*)(wsp + base_need);
  float* agg   = (float*)d_out;

  if (use_hbf) {
    hcvt_kernel<<<dim3(2048), dim3(256), 0, stream>>>(h, hb);
  }
  knn_kernel<<<dim3(1024), dim3(512), 0, stream>>>(pos, eidx, edist);
  if (use_hbf) {
    edge_kernel<true ><<<dim3(256), dim3(512), 0, stream>>>(h, hb, eidx, edist,
                                                            ew1, eb1, ew2, eb2, agg);
    node_kernel<true ><<<dim3(256), dim3(512), 0, stream>>>(h, hb, agg, nw1, nb1,
                                                            nw2, nb2, gam, bet, (float*)d_out);
  } else {
    edge_kernel<false><<<dim3(256), dim3(512), 0, stream>>>(h, hb, eidx, edist,
                                                            ew1, eb1, ew2, eb2, agg);
    node_kernel<false><<<dim3(256), dim3(512), 0, stream>>>(h, hb, agg, nw1, nb1,
                                                            nw2, nb2, gam, bet, (float*)d_out);
  }
}